// Round 12
// baseline (586.971 us; speedup 1.0000x reference)
//
#include <hip/hip_runtime.h>
#include <hip/hip_bf16.h>

#define N_NODES   20000
#define N_EDGES   160000
#define IN_DIM    64
#define HID       256
#define EDGE_DIM  64
#define NUM_GRAPHS 128
#define N_LAYERS  3

typedef __attribute__((ext_vector_type(8))) short s16x8;
typedef __attribute__((ext_vector_type(4))) float f32x4;

static __device__ __forceinline__ unsigned short f2bu(float f) {
    union { __hip_bfloat16 h; unsigned short u; } cv;
    cv.h = __float2bfloat16(f);
    return cv.u;
}
static __device__ __forceinline__ float bu2f(unsigned short u) {
    union { float f; unsigned int i; } c;
    c.i = ((unsigned int)u) << 16;
    return c.f;
}
static __device__ __forceinline__ s16x8 pack8(const float4 a, const float4 b) {
    s16x8 p;
    p[0] = (short)f2bu(a.x); p[1] = (short)f2bu(a.y);
    p[2] = (short)f2bu(a.z); p[3] = (short)f2bu(a.w);
    p[4] = (short)f2bu(b.x); p[5] = (short)f2bu(b.y);
    p[6] = (short)f2bu(b.z); p[7] = (short)f2bu(b.w);
    return p;
}

#define TILE_SH 8192   // [256 cols][32 k] bf16
// A tile: 64 rows x 128 shorts (256B), XOR-swizzled 16B slots (16 slots/row).
#define AIDX128(row, slot) ((row) * 128 + (((slot) ^ ((row) & 15)) << 3))
// Ts tile: 64 rows x 256 shorts, XOR-swizzled 8-short slots (32 slots/row).
static __device__ __forceinline__ int tsidx(int row, int col) {
    return row * 256 + ((((col >> 3) ^ (row & 15)) << 3) | (col & 7));
}
#define SMEM_BYTES 32768   // As 2*64*128*2 = 32768 == Ts 64*256*2

// ---------------------------------------------------------------- sort kernels
__global__ __launch_bounds__(256) void k_deg(const int* __restrict__ el,
                                             int* __restrict__ deg) {
    const int e = blockIdx.x * 256 + threadIdx.x;
    if (e < N_EDGES) atomicAdd(&deg[el[2 * e + 1]], 1);
}

__global__ __launch_bounds__(256) void k_scan(const int* __restrict__ deg,
                                              int* __restrict__ off,
                                              int* __restrict__ cursor) {
    __shared__ int ts[256];
    const int t = threadIdx.x;
    const int base = t * 79;
    const int end  = (base + 79 < N_NODES) ? base + 79 : N_NODES;
    int s = 0;
    for (int i = base; i < end; ++i) s += deg[i];
    ts[t] = s;
    __syncthreads();
    for (int d = 1; d < 256; d <<= 1) {
        const int u = (t >= d) ? ts[t - d] : 0;
        __syncthreads();
        ts[t] += u;
        __syncthreads();
    }
    int run = (t == 0) ? 0 : ts[t - 1];
    for (int i = base; i < end; ++i) {
        off[i] = run; cursor[i] = run; run += deg[i];
    }
}

__global__ __launch_bounds__(256) void k_scat(const int* __restrict__ el,
                                              int* __restrict__ cursor,
                                              int* __restrict__ eidx) {
    const int e = blockIdx.x * 256 + threadIdx.x;
    if (e < N_EDGES) {
        const int d = el[2 * e + 1];
        const int p = atomicAdd(&cursor[d], 1);
        eidx[p] = e;
    }
}

// ---------------------------------------------------------------- k_prep (weights -> bf16 tiles)
__global__ __launch_bounds__(256) void k_prep(const float* __restrict__ mW1,
                                              const float* __restrict__ mW2,
                                              const float* __restrict__ uW1,
                                              const float* __restrict__ uW2,
                                              unsigned short* __restrict__ msgW1T,
                                              unsigned short* __restrict__ msgW2T,
                                              unsigned short* __restrict__ updW1T,
                                              unsigned short* __restrict__ updW2T) {
    const int b = blockIdx.x;
    const int l = b / 50, t = b % 50;
    const float* W; unsigned short* dst; int rowbase;
    if (t < 18) {
        W = mW1 + (size_t)l * 578 * 256;
        dst = msgW1T + ((size_t)l * 18 + t) * TILE_SH;
        rowbase = (t < 16) ? t * 32 : 514 + (t - 16) * 32;
    } else if (t < 26) {
        const int tt = t - 18;
        W = mW2 + (size_t)l * 65536;
        dst = msgW2T + ((size_t)l * 8 + tt) * TILE_SH;
        rowbase = tt * 32;
    } else if (t < 42) {
        const int tt = t - 26;
        W = uW1 + (size_t)l * 131072;
        dst = updW1T + ((size_t)l * 16 + tt) * TILE_SH;
        rowbase = tt * 32;
    } else {
        const int tt = t - 42;
        W = uW2 + (size_t)l * 65536;
        dst = updW2T + ((size_t)l * 8 + tt) * TILE_SH;
        rowbase = tt * 32;
    }
    const int c = threadIdx.x;
    unsigned short buf[32];
    #pragma unroll
    for (int kk = 0; kk < 32; ++kk)
        buf[kk] = f2bu(W[(size_t)(rowbase + kk) * 256 + c]);
    #pragma unroll
    for (int j = 0; j < 4; ++j)
        *(s16x8*)&dst[(size_t)c * 32 + j * 8] = *(const s16x8*)&buf[j * 8];
}

// ---------------------------------------------------------------- k_pef (edge features -> bf16)
__global__ __launch_bounds__(256) void k_pef(const float* __restrict__ ef,
                                             unsigned short* __restrict__ efbf) {
    const size_t i = ((size_t)blockIdx.x * 256 + threadIdx.x) * 8;
    const float4 a = *(const float4*)&ef[i];
    const float4 b = *(const float4*)&ef[i + 4];
    *(s16x8*)&efbf[i] = pack8(a, b);
}

// ---------------------------------------------------------------- k_lin (h = x@W + b, bf16 out)
__global__ __launch_bounds__(256) void k_lin(const float* __restrict__ x,
                                             const float* __restrict__ W,
                                             const float* __restrict__ b,
                                             unsigned short* __restrict__ h) {
    __shared__ float Xs[16][68];
    const int tid = threadIdx.x;
    const int n0  = blockIdx.x * 16;
    {
        const int row = tid >> 4, q = tid & 15;
        const float4 v = *(const float4*)&x[(size_t)(n0 + row) * IN_DIM + q * 4];
        Xs[row][q * 4 + 0] = v.x; Xs[row][q * 4 + 1] = v.y;
        Xs[row][q * 4 + 2] = v.z; Xs[row][q * 4 + 3] = v.w;
    }
    __syncthreads();
    const int col = tid;
    float acc[16];
    #pragma unroll
    for (int r = 0; r < 16; ++r) acc[r] = 0.f;
    for (int k = 0; k < IN_DIM; ++k) {
        const float w = W[(size_t)k * HID + col];
        #pragma unroll
        for (int r = 0; r < 16; ++r) acc[r] += Xs[r][k] * w;
    }
    const float bb = b[col];
    #pragma unroll
    for (int r = 0; r < 16; ++r)
        h[(size_t)(n0 + r) * HID + col] = f2bu(acc[r] + bb);
}

// ---------------------------------------------------------------- k_msg
// Round-9 structure with K=128 chunks: GEMM1 = 4 full chunks (h|h) + 1 half
// chunk (ef); 64 MFMA per barrier, 5 staging barriers (was 9). A LDS double-
// buffer XOR-swizzled over 16 slots; Ts swizzled [64][256]. B direct-global,
// single-step prefetch. Run-length merged scatter epilogue.
__global__ __launch_bounds__(256, 3) void k_msg(const unsigned short* __restrict__ hbf,
                                                const float* __restrict__ sf,
                                                const unsigned short* __restrict__ efbf,
                                                const float* __restrict__ ew,
                                                const int*   __restrict__ el,
                                                const int*   __restrict__ eidx,
                                                const unsigned short* __restrict__ W1T,
                                                const float* __restrict__ W1f,
                                                const float* __restrict__ b1,
                                                const unsigned short* __restrict__ W2T,
                                                const float* __restrict__ b2,
                                                float* __restrict__ upd) {
    __shared__ __align__(16) unsigned char smem[SMEM_BYTES];   // As | Ts union
    __shared__ int   Se[64], Sni[64], Sno[64];
    __shared__ float Sew[64], Ssa[64], Ssb[64];
    unsigned short (*As)[64 * 128] =
        reinterpret_cast<unsigned short (*)[64 * 128]>(smem);
    unsigned short* Ts = reinterpret_cast<unsigned short*>(smem);

    const int tid = threadIdx.x;
    const int e0  = blockIdx.x * 64;
    if (tid < 64) {
        const int e = eidx[e0 + tid];
        const int a = el[2 * e], bn = el[2 * e + 1];
        Se[tid] = e; Sni[tid] = a; Sno[tid] = bn;
        Sew[tid] = ew[e]; Ssa[tid] = sf[a]; Ssb[tid] = sf[bn];
    }
    __syncthreads();

    const int lane = tid & 63, wv = tid >> 6;
    const int lr = lane & 15, lq = lane >> 4;
    const int arow = tid & 63;       // staging row
    const int g    = tid >> 6;       // staging group: 32 shorts (4 slots) per thread
    const int ni = Sni[arow], no = Sno[arow], myE = Se[arow];

    const unsigned short* bp1 = W1T + (size_t)(wv * 64 + lr) * 32 + lq * 8;
    const unsigned short* bp2 = W2T + (size_t)(wv * 64 + lr) * 32 + lq * 8;

    // per-chunk A source (full chunks c=0..3: 32 shorts/thread)
    #define APTR(c) ((c) < 2 ? hbf + (size_t)ni * HID + (c) * 128 + g * 32 \
                             : hbf + (size_t)no * HID + ((c) - 2) * 128 + g * 32)

    f32x4 acc[4][4];
    #pragma unroll
    for (int i = 0; i < 4; ++i)
        #pragma unroll
        for (int j = 0; j < 4; ++j) acc[i][j] = (f32x4)(0.0f);

    // prologue: chunk0 -> LDS buf0; chunk1 -> regs; B tile0 -> regs
    {
        const unsigned short* ap = APTR(0);
        #pragma unroll
        for (int j = 0; j < 4; ++j)
            *(s16x8*)&As[0][AIDX128(arow, 4 * g + j)] = *(const s16x8*)(ap + 8 * j);
    }
    s16x8 rN[4], rF[4];
    {
        const unsigned short* ap = APTR(1);
        #pragma unroll
        for (int j = 0; j < 4; ++j) rN[j] = *(const s16x8*)(ap + 8 * j);
    }
    s16x8 bfr[4], nb[4];
    #pragma unroll
    for (int nf = 0; nf < 4; ++nf)
        bfr[nf] = *(const s16x8*)(bp1 + nf * 512);
    __syncthreads();

    // ---------------- GEMM1 : 4 full K=128 chunks ----------------
    for (int c = 0; c < 4; ++c) {
        if (c + 2 < 4) {          // full-chunk gather for c+2
            const unsigned short* ap = APTR(c + 2);
            #pragma unroll
            for (int j = 0; j < 4; ++j) rF[j] = *(const s16x8*)(ap + 8 * j);
        } else if (c + 2 == 4) {  // half-chunk gather (ef): 16 shorts/thread
            const unsigned short* ap = efbf + (size_t)myE * EDGE_DIM + g * 16;
            rF[0] = *(const s16x8*)(ap);
            rF[1] = *(const s16x8*)(ap + 8);
        }
        #pragma unroll
        for (int ks = 0; ks < 4; ++ks) {
            const int t = c * 4 + ks;            // 0..15, B tiles 0..17 exist
            s16x8 af[4];
            #pragma unroll
            for (int mf = 0; mf < 4; ++mf)
                af[mf] = *(const s16x8*)&As[c & 1][AIDX128(mf * 16 + lr, ks * 4 + lq)];
            #pragma unroll
            for (int nf = 0; nf < 4; ++nf)
                nb[nf] = *(const s16x8*)(bp1 + (size_t)(t + 1) * TILE_SH + nf * 512);
            #pragma unroll
            for (int mf = 0; mf < 4; ++mf)
                #pragma unroll
                for (int nf = 0; nf < 4; ++nf)
                    acc[mf][nf] = __builtin_amdgcn_mfma_f32_16x16x32_bf16(
                        af[mf], bfr[nf], acc[mf][nf], 0, 0, 0);
            #pragma unroll
            for (int nf = 0; nf < 4; ++nf) bfr[nf] = nb[nf];
        }
        if (c < 3) {              // stage full chunk c+1
            #pragma unroll
            for (int j = 0; j < 4; ++j)
                *(s16x8*)&As[(c + 1) & 1][AIDX128(arow, 4 * g + j)] = rN[j];
            #pragma unroll
            for (int j = 0; j < 4; ++j) rN[j] = rF[j];
        } else {                  // stage half chunk 4 (ef) into buf0, slots 0..7
            *(s16x8*)&As[0][AIDX128(arow, 2 * g)]     = rN[0];
            *(s16x8*)&As[0][AIDX128(arow, 2 * g + 1)] = rN[1];
        }
        __syncthreads();
    }
    // ---- chunk 4 (ef, K=64, buf0) ----
    #pragma unroll
    for (int ks = 0; ks < 2; ++ks) {
        const int t = 16 + ks;
        s16x8 af[4];
        #pragma unroll
        for (int mf = 0; mf < 4; ++mf)
            af[mf] = *(const s16x8*)&As[0][AIDX128(mf * 16 + lr, ks * 4 + lq)];
        if (t + 1 < 18) {
            #pragma unroll
            for (int nf = 0; nf < 4; ++nf)
                nb[nf] = *(const s16x8*)(bp1 + (size_t)(t + 1) * TILE_SH + nf * 512);
        }
        #pragma unroll
        for (int mf = 0; mf < 4; ++mf)
            #pragma unroll
            for (int nf = 0; nf < 4; ++nf)
                acc[mf][nf] = __builtin_amdgcn_mfma_f32_16x16x32_bf16(
                    af[mf], bfr[nf], acc[mf][nf], 0, 0, 0);
        if (t + 1 < 18) {
            #pragma unroll
            for (int nf = 0; nf < 4; ++nf) bfr[nf] = nb[nf];
        }
    }
    #undef APTR

    // prefetch GEMM2 B tile0 — hides under epilogue 1 + barrier
    s16x8 b2f[4], n2b[4];
    #pragma unroll
    for (int nf = 0; nf < 4; ++nf)
        b2f[nf] = *(const s16x8*)(bp2 + nf * 512);

    // all waves must finish As reads before Ts (aliased) is written
    __syncthreads();

    // epilogue 1: sf rank-1 + bias + relu -> Ts (bf16, swizzled)
    #pragma unroll
    for (int nf = 0; nf < 4; ++nf) {
        const int col = wv * 64 + nf * 16 + lr;
        const float w512 = W1f[(size_t)512 * HID + col];
        const float w513 = W1f[(size_t)513 * HID + col];
        const float bb   = b1[col];
        #pragma unroll
        for (int mf = 0; mf < 4; ++mf)
            #pragma unroll
            for (int r = 0; r < 4; ++r) {
                const int row = mf * 16 + lq * 4 + r;
                float v = acc[mf][nf][r] + Ssa[row] * w512 + Ssb[row] * w513 + bb;
                Ts[tsidx(row, col)] = f2bu(fmaxf(v, 0.f));
            }
    }
    __syncthreads();

    // ---------------- GEMM2 : 8 K-steps, barrier-free ----------------
    f32x4 acc2[4][4];
    #pragma unroll
    for (int i = 0; i < 4; ++i)
        #pragma unroll
        for (int j = 0; j < 4; ++j) acc2[i][j] = (f32x4)(0.0f);

    for (int s = 0; s < 8; ++s) {
        s16x8 a2[4];
        #pragma unroll
        for (int mf = 0; mf < 4; ++mf)
            a2[mf] = *(const s16x8*)&Ts[tsidx(mf * 16 + lr, s * 32 + lq * 8)];
        if (s + 1 < 8) {
            #pragma unroll
            for (int nf = 0; nf < 4; ++nf)
                n2b[nf] = *(const s16x8*)(bp2 + (size_t)(s + 1) * TILE_SH + nf * 512);
        }
        #pragma unroll
        for (int mf = 0; mf < 4; ++mf)
            #pragma unroll
            for (int nf = 0; nf < 4; ++nf)
                acc2[mf][nf] = __builtin_amdgcn_mfma_f32_16x16x32_bf16(
                    a2[mf], b2f[nf], acc2[mf][nf], 0, 0, 0);
        if (s + 1 < 8) {
            #pragma unroll
            for (int nf = 0; nf < 4; ++nf) b2f[nf] = n2b[nf];
        }
    }

    // epilogue 2: run-length merged scatter, two 128-col halves via LDS (fp32)
    float* Mf = (float*)Ts;
    #pragma unroll
    for (int half = 0; half < 2; ++half) {
        __syncthreads();
        if ((wv >> 1) == half) {
            #pragma unroll
            for (int nf = 0; nf < 4; ++nf) {
                const int c  = (wv & 1) * 64 + nf * 16 + lr;
                const float bb = b2[half * 128 + c];
                #pragma unroll
                for (int mf = 0; mf < 4; ++mf)
                    #pragma unroll
                    for (int r = 0; r < 4; ++r) {
                        const int row = mf * 16 + lq * 4 + r;
                        Mf[row * 128 + c] = (acc2[mf][nf][r] + bb) * Sew[row];
                    }
            }
        }
        __syncthreads();
        {
            const int c = tid & 127;
            const int colg = half * 128 + c;
            const int rbase = (tid >> 7) * 32;
            float a = 0.f;
            int cur = Sno[rbase];
            for (int r = rbase; r < rbase + 32; ++r) {
                const int gno = Sno[r];
                if (gno != cur) {
                    atomicAdd(&upd[(size_t)cur * HID + colg], a);
                    a = 0.f; cur = gno;
                }
                a += Mf[r * 128 + c];
            }
            atomicAdd(&upd[(size_t)cur * HID + colg], a);
        }
    }
}

// ---------------------------------------------------------------- k_upd
// K=512 in 4 full K=128 chunks (h bf16 copy / upd fp32+cvt); GEMM2 8 steps.
__global__ __launch_bounds__(256, 3) void k_upd(const unsigned short* __restrict__ hbf,
                                                const float* __restrict__ upd,
                                                const unsigned short* __restrict__ W1T,
                                                const float* __restrict__ b1,
                                                const unsigned short* __restrict__ W2T,
                                                const float* __restrict__ b2,
                                                unsigned short* __restrict__ hout) {
    __shared__ __align__(16) unsigned char smem[SMEM_BYTES];
    unsigned short (*As)[64 * 128] =
        reinterpret_cast<unsigned short (*)[64 * 128]>(smem);
    unsigned short* Ts = reinterpret_cast<unsigned short*>(smem);

    const int tid = threadIdx.x;
    const int n0  = blockIdx.x * 64;
    const int lane = tid & 63, wv = tid >> 6;
    const int lr = lane & 15, lq = lane >> 4;
    const int arow = tid & 63;
    const int g    = tid >> 6;
    const int node = (n0 + arow < N_NODES) ? (n0 + arow) : (N_NODES - 1);

    const unsigned short* bp1 = W1T + (size_t)(wv * 64 + lr) * 32 + lq * 8;
    const unsigned short* bp2 = W2T + (size_t)(wv * 64 + lr) * 32 + lq * 8;

    f32x4 acc[4][4];
    #pragma unroll
    for (int i = 0; i < 4; ++i)
        #pragma unroll
        for (int j = 0; j < 4; ++j) acc[i][j] = (f32x4)(0.0f);

    // chunk c -> four s16x8 (c<2: h bf16; c>=2: upd fp32 + cvt)
    #define ULOAD(c, r_) do { \
        if ((c) < 2) { \
            const unsigned short* ap = hbf + (size_t)node * HID + (c) * 128 + g * 32; \
            r_[0] = *(const s16x8*)(ap);      r_[1] = *(const s16x8*)(ap + 8); \
            r_[2] = *(const s16x8*)(ap + 16); r_[3] = *(const s16x8*)(ap + 24); \
        } else { \
            const float* up = upd + (size_t)node * HID + ((c) - 2) * 128 + g * 32; \
            r_[0] = pack8(*(const float4*)(up),      *(const float4*)(up + 4)); \
            r_[1] = pack8(*(const float4*)(up + 8),  *(const float4*)(up + 12)); \
            r_[2] = pack8(*(const float4*)(up + 16), *(const float4*)(up + 20)); \
            r_[3] = pack8(*(const float4*)(up + 24), *(const float4*)(up + 28)); \
        } } while (0)

    {
        s16x8 t0[4];
        ULOAD(0, t0);
        #pragma unroll
        for (int j = 0; j < 4; ++j)
            *(s16x8*)&As[0][AIDX128(arow, 4 * g + j)] = t0[j];
    }
    s16x8 rN[4], rF[4];
    ULOAD(1, rN);
    s16x8 bfr[4], nb[4];
    #pragma unroll
    for (int nf = 0; nf < 4; ++nf)
        bfr[nf] = *(const s16x8*)(bp1 + nf * 512);
    __syncthreads();

    for (int c = 0; c < 4; ++c) {
        if (c + 2 < 4) ULOAD(c + 2, rF);
        #pragma unroll
        for (int ks = 0; ks < 4; ++ks) {
            const int t = c * 4 + ks;            // 0..15
            s16x8 af[4];
            #pragma unroll
            for (int mf = 0; mf < 4; ++mf)
                af[mf] = *(const s16x8*)&As[c & 1][AIDX128(mf * 16 + lr, ks * 4 + lq)];
            if (t + 1 < 16) {
                #pragma unroll
                for (int nf = 0; nf < 4; ++nf)
                    nb[nf] = *(const s16x8*)(bp1 + (size_t)(t + 1) * TILE_SH + nf * 512);
            }
            #pragma unroll
            for (int mf = 0; mf < 4; ++mf)
                #pragma unroll
                for (int nf = 0; nf < 4; ++nf)
                    acc[mf][nf] = __builtin_amdgcn_mfma_f32_16x16x32_bf16(
                        af[mf], bfr[nf], acc[mf][nf], 0, 0, 0);
            if (t + 1 < 16) {
                #pragma unroll
                for (int nf = 0; nf < 4; ++nf) bfr[nf] = nb[nf];
            }
        }
        if (c + 1 < 4) {
            #pragma unroll
            for (int j = 0; j < 4; ++j)
                *(s16x8*)&As[(c + 1) & 1][AIDX128(arow, 4 * g + j)] = rN[j];
            #pragma unroll
            for (int j = 0; j < 4; ++j) rN[j] = rF[j];
            __syncthreads();
        }
    }
    #undef ULOAD

    // prefetch GEMM2 B tile0 — hides under epilogue
    s16x8 b2f[4], n2b[4];
    #pragma unroll
    for (int nf = 0; nf < 4; ++nf)
        b2f[nf] = *(const s16x8*)(bp2 + nf * 512);

    // all waves must finish As reads before Ts (aliased) is written
    __syncthreads();

    #pragma unroll
    for (int nf = 0; nf < 4; ++nf) {
        const int col = wv * 64 + nf * 16 + lr;
        const float bb = b1[col];
        #pragma unroll
        for (int mf = 0; mf < 4; ++mf)
            #pragma unroll
            for (int r = 0; r < 4; ++r) {
                const int row = mf * 16 + lq * 4 + r;
                Ts[tsidx(row, col)] = f2bu(fmaxf(acc[mf][nf][r] + bb, 0.f));
            }
    }
    __syncthreads();

    f32x4 acc2[4][4];
    #pragma unroll
    for (int i = 0; i < 4; ++i)
        #pragma unroll
        for (int j = 0; j < 4; ++j) acc2[i][j] = (f32x4)(0.0f);

    for (int s = 0; s < 8; ++s) {
        s16x8 a2[4];
        #pragma unroll
        for (int mf = 0; mf < 4; ++mf)
            a2[mf] = *(const s16x8*)&Ts[tsidx(mf * 16 + lr, s * 32 + lq * 8)];
        if (s + 1 < 8) {
            #pragma unroll
            for (int nf = 0; nf < 4; ++nf)
                n2b[nf] = *(const s16x8*)(bp2 + (size_t)(s + 1) * TILE_SH + nf * 512);
        }
        #pragma unroll
        for (int mf = 0; mf < 4; ++mf)
            #pragma unroll
            for (int nf = 0; nf < 4; ++nf)
                acc2[mf][nf] = __builtin_amdgcn_mfma_f32_16x16x32_bf16(
                    a2[mf], b2f[nf], acc2[mf][nf], 0, 0, 0);
        if (s + 1 < 8) {
            #pragma unroll
            for (int nf = 0; nf < 4; ++nf) b2f[nf] = n2b[nf];
        }
    }

    #pragma unroll
    for (int nf = 0; nf < 4; ++nf) {
        const int col = wv * 64 + nf * 16 + lr;
        const float bb = b2[col];
        #pragma unroll
        for (int mf = 0; mf < 4; ++mf)
            #pragma unroll
            for (int r = 0; r < 4; ++r) {
                const int row = mf * 16 + lq * 4 + r;
                const int n = n0 + row;
                if (n < N_NODES)
                    hout[(size_t)n * HID + col] = f2bu(fmaxf(acc2[mf][nf][r] + bb, 0.f));
            }
    }
}

// ---------------------------------------------------------------- k_graph (bf16 h in)
__global__ __launch_bounds__(256) void k_graph(const unsigned short* __restrict__ h,
                                               const int* __restrict__ n2g,
                                               float* __restrict__ out) {
    __shared__ int Sg[64];
    const int tid = threadIdx.x;
    const int n0  = blockIdx.x * 64;
    if (tid < 64) {
        const int n = n0 + tid;
        Sg[tid] = (n < N_NODES) ? n2g[n] : -1;
    }
    __syncthreads();
    const int col = tid;
    float accv = 0.f;
    int curg = Sg[0];
    for (int r = 0; r < 64; ++r) {
        const int n = n0 + r;
        if (n >= N_NODES) break;
        const int g = Sg[r];
        if (g != curg) {
            atomicAdd(&out[(size_t)curg * HID + col], accv);
            accv = 0.f; curg = g;
        }
        accv += bu2f(h[(size_t)n * HID + col]);
    }
    atomicAdd(&out[(size_t)curg * HID + col], accv);
}

// ---------------------------------------------------------------- launch
extern "C" void kernel_launch(void* const* d_in, const int* in_sizes, int n_in,
                              void* d_out, int out_size, void* d_ws, size_t ws_size,
                              hipStream_t stream) {
    const float* x    = (const float*)d_in[0];
    const float* sf   = (const float*)d_in[1];
    const float* ef   = (const float*)d_in[2];
    const float* ew   = (const float*)d_in[3];
    const int*   el   = (const int*)d_in[4];
    const int*   n2g  = (const int*)d_in[5];
    const float* Wlin = (const float*)d_in[6];
    const float* blin = (const float*)d_in[7];
    const float* mW1  = (const float*)d_in[8];
    const float* mb1  = (const float*)d_in[9];
    const float* mW2  = (const float*)d_in[10];
    const float* mb2  = (const float*)d_in[11];
    const float* uW1  = (const float*)d_in[12];
    const float* ub1  = (const float*)d_in[13];
    const float* uW2  = (const float*)d_in[14];
    const float* ub2  = (const float*)d_in[15];
    float* out = (float*)d_out;

    unsigned short* hA   = (unsigned short*)d_ws;                  // N_NODES*HID bf16
    unsigned short* hB   = hA + (size_t)N_NODES * HID;
    unsigned short* efbf = hB + (size_t)N_NODES * HID;             // N_EDGES*EDGE_DIM bf16
    unsigned short* msgW1T = efbf + (size_t)N_EDGES * EDGE_DIM;    // 3*18*8192
    unsigned short* msgW2T = msgW1T + (size_t)3 * 18 * TILE_SH;    // 3*8*8192
    unsigned short* updW1T = msgW2T + (size_t)3 * 8  * TILE_SH;    // 3*16*8192
    unsigned short* updW2T = updW1T + (size_t)3 * 16 * TILE_SH;    // 3*8*8192
    float* upd  = (float*)(updW2T + (size_t)3 * 8 * TILE_SH);      // N_NODES*HID f32
    int* deg    = (int*)(upd + (size_t)N_NODES * HID);
    int* off    = deg + N_NODES;
    int* cursor = off + N_NODES;
    int* eidx   = cursor + N_NODES;                                // N_EDGES

    hipMemsetAsync(d_out, 0, (size_t)NUM_GRAPHS * HID * sizeof(float), stream);
    hipMemsetAsync(deg, 0, (size_t)N_NODES * sizeof(int), stream);

    k_deg <<<(N_EDGES + 255) / 256, 256, 0, stream>>>(el, deg);
    k_scan<<<1, 256, 0, stream>>>(deg, off, cursor);
    k_scat<<<(N_EDGES + 255) / 256, 256, 0, stream>>>(el, cursor, eidx);

    k_prep<<<150, 256, 0, stream>>>(mW1, mW2, uW1, uW2,
                                    msgW1T, msgW2T, updW1T, updW2T);
    k_pef <<<N_EDGES * EDGE_DIM / (256 * 8), 256, 0, stream>>>(ef, efbf);
    k_lin <<<N_NODES / 16, 256, 0, stream>>>(x, Wlin, blin, hA);

    unsigned short* hc = hA;
    unsigned short* hn = hB;
    for (int l = 0; l < N_LAYERS; ++l) {
        hipMemsetAsync(upd, 0, (size_t)N_NODES * HID * sizeof(float), stream);
        k_msg<<<N_EDGES / 64, 256, 0, stream>>>(
            hc, sf, efbf, ew, el, eidx,
            msgW1T + (size_t)l * 18 * TILE_SH,
            mW1 + (size_t)l * 578 * 256, mb1 + (size_t)l * HID,
            msgW2T + (size_t)l * 8 * TILE_SH, mb2 + (size_t)l * HID, upd);
        k_upd<<<(N_NODES + 63) / 64, 256, 0, stream>>>(
            hc, upd,
            updW1T + (size_t)l * 16 * TILE_SH, ub1 + (size_t)l * HID,
            updW2T + (size_t)l * 8 * TILE_SH,  ub2 + (size_t)l * HID, hn);
        unsigned short* t = hc; hc = hn; hn = t;
    }

    k_graph<<<(N_NODES + 63) / 64, 256, 0, stream>>>(hc, n2g, out);
}

// Round 13
// 538.749 us; speedup vs baseline: 1.0895x; 1.0895x over previous
//
#include <hip/hip_runtime.h>
#include <hip/hip_bf16.h>

#define N_NODES   20000
#define N_EDGES   160000
#define IN_DIM    64
#define HID       256
#define EDGE_DIM  64
#define NUM_GRAPHS 128
#define N_LAYERS  3

typedef __attribute__((ext_vector_type(8))) short s16x8;
typedef __attribute__((ext_vector_type(4))) float f32x4;

static __device__ __forceinline__ unsigned short f2bu(float f) {
    union { __hip_bfloat16 h; unsigned short u; } cv;
    cv.h = __float2bfloat16(f);
    return cv.u;
}
static __device__ __forceinline__ float bu2f(unsigned short u) {
    union { float f; unsigned int i; } c;
    c.i = ((unsigned int)u) << 16;
    return c.f;
}
static __device__ __forceinline__ s16x8 pack8(const float4 a, const float4 b) {
    s16x8 p;
    p[0] = (short)f2bu(a.x); p[1] = (short)f2bu(a.y);
    p[2] = (short)f2bu(a.z); p[3] = (short)f2bu(a.w);
    p[4] = (short)f2bu(b.x); p[5] = (short)f2bu(b.y);
    p[6] = (short)f2bu(b.z); p[7] = (short)f2bu(b.w);
    return p;
}

#define TILE_SH 8192   // [256 cols][32 k] bf16
// A tile: 64 rows x 64 shorts (128B), XOR-swizzled 16B slots.
#define AIDX(row, slot) ((row) * 64 + (((slot) ^ ((row) & 7)) << 3))
#define SMEM_BYTES 33792   // max(As 2*64*64*2 = 16384, Ts 64*264*2 = 33792)

// ---------------------------------------------------------------- sort kernels
__global__ __launch_bounds__(256) void k_deg(const int* __restrict__ el,
                                             int* __restrict__ deg) {
    const int e = blockIdx.x * 256 + threadIdx.x;
    if (e < N_EDGES) atomicAdd(&deg[el[2 * e + 1]], 1);
}

__global__ __launch_bounds__(256) void k_scan(const int* __restrict__ deg,
                                              int* __restrict__ off,
                                              int* __restrict__ cursor) {
    __shared__ int ts[256];
    const int t = threadIdx.x;
    const int base = t * 79;
    const int end  = (base + 79 < N_NODES) ? base + 79 : N_NODES;
    int s = 0;
    for (int i = base; i < end; ++i) s += deg[i];
    ts[t] = s;
    __syncthreads();
    for (int d = 1; d < 256; d <<= 1) {
        const int u = (t >= d) ? ts[t - d] : 0;
        __syncthreads();
        ts[t] += u;
        __syncthreads();
    }
    int run = (t == 0) ? 0 : ts[t - 1];
    for (int i = base; i < end; ++i) {
        off[i] = run; cursor[i] = run; run += deg[i];
    }
}

__global__ __launch_bounds__(256) void k_scat(const int* __restrict__ el,
                                              int* __restrict__ cursor,
                                              int* __restrict__ eidx) {
    const int e = blockIdx.x * 256 + threadIdx.x;
    if (e < N_EDGES) {
        const int d = el[2 * e + 1];
        const int p = atomicAdd(&cursor[d], 1);
        eidx[p] = e;
    }
}

// ---------------------------------------------------------------- k_prep (weights -> bf16 tiles)
__global__ __launch_bounds__(256) void k_prep(const float* __restrict__ mW1,
                                              const float* __restrict__ mW2,
                                              const float* __restrict__ uW1,
                                              const float* __restrict__ uW2,
                                              unsigned short* __restrict__ msgW1T,
                                              unsigned short* __restrict__ msgW2T,
                                              unsigned short* __restrict__ updW1T,
                                              unsigned short* __restrict__ updW2T) {
    const int b = blockIdx.x;
    const int l = b / 50, t = b % 50;
    const float* W; unsigned short* dst; int rowbase;
    if (t < 18) {
        W = mW1 + (size_t)l * 578 * 256;
        dst = msgW1T + ((size_t)l * 18 + t) * TILE_SH;
        rowbase = (t < 16) ? t * 32 : 514 + (t - 16) * 32;
    } else if (t < 26) {
        const int tt = t - 18;
        W = mW2 + (size_t)l * 65536;
        dst = msgW2T + ((size_t)l * 8 + tt) * TILE_SH;
        rowbase = tt * 32;
    } else if (t < 42) {
        const int tt = t - 26;
        W = uW1 + (size_t)l * 131072;
        dst = updW1T + ((size_t)l * 16 + tt) * TILE_SH;
        rowbase = tt * 32;
    } else {
        const int tt = t - 42;
        W = uW2 + (size_t)l * 65536;
        dst = updW2T + ((size_t)l * 8 + tt) * TILE_SH;
        rowbase = tt * 32;
    }
    const int c = threadIdx.x;
    unsigned short buf[32];
    #pragma unroll
    for (int kk = 0; kk < 32; ++kk)
        buf[kk] = f2bu(W[(size_t)(rowbase + kk) * 256 + c]);
    #pragma unroll
    for (int j = 0; j < 4; ++j)
        *(s16x8*)&dst[(size_t)c * 32 + j * 8] = *(const s16x8*)&buf[j * 8];
}

// ---------------------------------------------------------------- k_pef (edge features -> bf16)
__global__ __launch_bounds__(256) void k_pef(const float* __restrict__ ef,
                                             unsigned short* __restrict__ efbf) {
    const size_t i = ((size_t)blockIdx.x * 256 + threadIdx.x) * 8;
    const float4 a = *(const float4*)&ef[i];
    const float4 b = *(const float4*)&ef[i + 4];
    *(s16x8*)&efbf[i] = pack8(a, b);
}

// ---------------------------------------------------------------- k_lin (h = x@W + b, bf16 out)
__global__ __launch_bounds__(256) void k_lin(const float* __restrict__ x,
                                             const float* __restrict__ W,
                                             const float* __restrict__ b,
                                             unsigned short* __restrict__ h) {
    __shared__ float Xs[16][68];
    const int tid = threadIdx.x;
    const int n0  = blockIdx.x * 16;
    {
        const int row = tid >> 4, q = tid & 15;
        const float4 v = *(const float4*)&x[(size_t)(n0 + row) * IN_DIM + q * 4];
        Xs[row][q * 4 + 0] = v.x; Xs[row][q * 4 + 1] = v.y;
        Xs[row][q * 4 + 2] = v.z; Xs[row][q * 4 + 3] = v.w;
    }
    __syncthreads();
    const int col = tid;
    float acc[16];
    #pragma unroll
    for (int r = 0; r < 16; ++r) acc[r] = 0.f;
    for (int k = 0; k < IN_DIM; ++k) {
        const float w = W[(size_t)k * HID + col];
        #pragma unroll
        for (int r = 0; r < 16; ++r) acc[r] += Xs[r][k] * w;
    }
    const float bb = b[col];
    #pragma unroll
    for (int r = 0; r < 16; ++r)
        h[(size_t)(n0 + r) * HID + col] = f2bu(acc[r] + bb);
}

// ---------------------------------------------------------------- k_msg
// 64 sorted-by-dest edges x 256 cols. Chunked K (64): A LDS double-buffer
// (XOR-swizzled) + 2-deep register gather pipeline; B direct-global.
// As/Ts LDS union -> 35.3KB; launch_bounds(256,3). Run-length merged scatter.
__global__ __launch_bounds__(256, 3) void k_msg(const unsigned short* __restrict__ hbf,
                                                const float* __restrict__ sf,
                                                const unsigned short* __restrict__ efbf,
                                                const float* __restrict__ ew,
                                                const int*   __restrict__ el,
                                                const int*   __restrict__ eidx,
                                                const unsigned short* __restrict__ W1T,
                                                const float* __restrict__ W1f,
                                                const float* __restrict__ b1,
                                                const unsigned short* __restrict__ W2T,
                                                const float* __restrict__ b2,
                                                float* __restrict__ upd) {
    __shared__ __align__(16) unsigned char smem[SMEM_BYTES];   // As | Ts union
    __shared__ int   Se[64], Sni[64], Sno[64];
    __shared__ float Sew[64], Ssa[64], Ssb[64];
    unsigned short (*As)[64 * 64] =
        reinterpret_cast<unsigned short (*)[64 * 64]>(smem);
    unsigned short* Ts = reinterpret_cast<unsigned short*>(smem);

    const int tid = threadIdx.x;
    const int e0  = blockIdx.x * 64;
    if (tid < 64) {
        const int e = eidx[e0 + tid];
        const int a = el[2 * e], bn = el[2 * e + 1];
        Se[tid] = e; Sni[tid] = a; Sno[tid] = bn;
        Sew[tid] = ew[e]; Ssa[tid] = sf[a]; Ssb[tid] = sf[bn];
    }
    __syncthreads();

    const int lane = tid & 63, wv = tid >> 6;
    const int lr = lane & 15, lq = lane >> 4;
    const int arow = tid & 63;           // staging row
    const int aoff = (tid >> 6) * 16;    // shorts within 64-short chunk
    const int ni = Sni[arow], no = Sno[arow], myE = Se[arow];

    const unsigned short* bp1 = W1T + (size_t)(wv * 64 + lr) * 32 + lq * 8;
    const unsigned short* bp2 = W2T + (size_t)(wv * 64 + lr) * 32 + lq * 8;

    // per-chunk A source for this thread's 32B slice
    #define APTR(c) ((c) < 4 ? hbf + (size_t)ni * HID + (c) * 64 + aoff \
                  : ((c) < 8 ? hbf + (size_t)no * HID + ((c) - 4) * 64 + aoff \
                             : efbf + (size_t)myE * EDGE_DIM + aoff))

    f32x4 acc[4][4];
    #pragma unroll
    for (int i = 0; i < 4; ++i)
        #pragma unroll
        for (int j = 0; j < 4; ++j) acc[i][j] = (f32x4)(0.0f);

    // prologue: chunk0 -> LDS buf0; chunk1 -> regs; B tile0 -> regs
    {
        const unsigned short* ap = APTR(0);
        *(s16x8*)&As[0][AIDX(arow, 2 * wv)]     = *(const s16x8*)(ap);
        *(s16x8*)&As[0][AIDX(arow, 2 * wv + 1)] = *(const s16x8*)(ap + 8);
    }
    s16x8 rNa, rNb, rFa, rFb;
    {
        const unsigned short* ap = APTR(1);
        rNa = *(const s16x8*)(ap);
        rNb = *(const s16x8*)(ap + 8);
    }
    s16x8 bfr[4], nb[4];
    #pragma unroll
    for (int nf = 0; nf < 4; ++nf)
        bfr[nf] = *(const s16x8*)(bp1 + nf * 512);
    __syncthreads();

    // ---------------- GEMM1 : 9 chunks of K=64 ----------------
    for (int c = 0; c < 9; ++c) {
        if (c + 2 < 9) {   // issue gather for chunk c+2
            const unsigned short* ap = APTR(c + 2);
            rFa = *(const s16x8*)(ap);
            rFb = *(const s16x8*)(ap + 8);
        }
        #pragma unroll
        for (int ksub = 0; ksub < 2; ++ksub) {
            const int t = c * 2 + ksub;
            s16x8 af[4];
            #pragma unroll
            for (int mf = 0; mf < 4; ++mf)
                af[mf] = *(const s16x8*)&As[c & 1][AIDX(mf * 16 + lr, ksub * 4 + lq)];
            if (t + 1 < 18) {
                #pragma unroll
                for (int nf = 0; nf < 4; ++nf)
                    nb[nf] = *(const s16x8*)(bp1 + (size_t)(t + 1) * TILE_SH + nf * 512);
            }
            #pragma unroll
            for (int mf = 0; mf < 4; ++mf)
                #pragma unroll
                for (int nf = 0; nf < 4; ++nf)
                    acc[mf][nf] = __builtin_amdgcn_mfma_f32_16x16x32_bf16(
                        af[mf], bfr[nf], acc[mf][nf], 0, 0, 0);
            if (t + 1 < 18) {
                #pragma unroll
                for (int nf = 0; nf < 4; ++nf) bfr[nf] = nb[nf];
            }
        }
        if (c + 1 < 9) {
            *(s16x8*)&As[(c + 1) & 1][AIDX(arow, 2 * wv)]     = rNa;
            *(s16x8*)&As[(c + 1) & 1][AIDX(arow, 2 * wv + 1)] = rNb;
            rNa = rFa; rNb = rFb;
            __syncthreads();
        }
    }
    #undef APTR

    // all waves must finish As reads before Ts (aliased) is written
    __syncthreads();

    // epilogue 1: sf rank-1 + bias + relu -> Ts (bf16)
    #pragma unroll
    for (int nf = 0; nf < 4; ++nf) {
        const int col = wv * 64 + nf * 16 + lr;
        const float w512 = W1f[(size_t)512 * HID + col];
        const float w513 = W1f[(size_t)513 * HID + col];
        const float bb   = b1[col];
        #pragma unroll
        for (int mf = 0; mf < 4; ++mf)
            #pragma unroll
            for (int r = 0; r < 4; ++r) {
                const int row = mf * 16 + lq * 4 + r;
                float v = acc[mf][nf][r] + Ssa[row] * w512 + Ssb[row] * w513 + bb;
                Ts[row * 264 + col] = f2bu(fmaxf(v, 0.f));
            }
    }
    __syncthreads();

    // ---------------- GEMM2 : 8 K-steps, barrier-free ----------------
    f32x4 acc2[4][4];
    #pragma unroll
    for (int i = 0; i < 4; ++i)
        #pragma unroll
        for (int j = 0; j < 4; ++j) acc2[i][j] = (f32x4)(0.0f);

    s16x8 b2f[4], n2b[4];
    #pragma unroll
    for (int nf = 0; nf < 4; ++nf)
        b2f[nf] = *(const s16x8*)(bp2 + nf * 512);

    for (int s = 0; s < 8; ++s) {
        s16x8 a2[4];
        #pragma unroll
        for (int mf = 0; mf < 4; ++mf)
            a2[mf] = *(const s16x8*)&Ts[(mf * 16 + lr) * 264 + s * 32 + lq * 8];
        if (s + 1 < 8) {
            #pragma unroll
            for (int nf = 0; nf < 4; ++nf)
                n2b[nf] = *(const s16x8*)(bp2 + (size_t)(s + 1) * TILE_SH + nf * 512);
        }
        #pragma unroll
        for (int mf = 0; mf < 4; ++mf)
            #pragma unroll
            for (int nf = 0; nf < 4; ++nf)
                acc2[mf][nf] = __builtin_amdgcn_mfma_f32_16x16x32_bf16(
                    a2[mf], b2f[nf], acc2[mf][nf], 0, 0, 0);
        if (s + 1 < 8) {
            #pragma unroll
            for (int nf = 0; nf < 4; ++nf) b2f[nf] = n2b[nf];
        }
    }

    // epilogue 2: run-length merged scatter, two 128-col halves via LDS (fp32)
    float* Mf = (float*)Ts;
    #pragma unroll
    for (int half = 0; half < 2; ++half) {
        __syncthreads();
        if ((wv >> 1) == half) {
            #pragma unroll
            for (int nf = 0; nf < 4; ++nf) {
                const int c  = (wv & 1) * 64 + nf * 16 + lr;
                const float bb = b2[half * 128 + c];
                #pragma unroll
                for (int mf = 0; mf < 4; ++mf)
                    #pragma unroll
                    for (int r = 0; r < 4; ++r) {
                        const int row = mf * 16 + lq * 4 + r;
                        Mf[row * 132 + c] = (acc2[mf][nf][r] + bb) * Sew[row];
                    }
            }
        }
        __syncthreads();
        {
            const int c = tid & 127;
            const int colg = half * 128 + c;
            const int rbase = (tid >> 7) * 32;
            float a = 0.f;
            int cur = Sno[rbase];
            for (int r = rbase; r < rbase + 32; ++r) {
                const int g = Sno[r];
                if (g != cur) {
                    atomicAdd(&upd[(size_t)cur * HID + colg], a);
                    a = 0.f; cur = g;
                }
                a += Mf[r * 132 + c];
            }
            atomicAdd(&upd[(size_t)cur * HID + colg], a);
        }
    }
}

// ---------------------------------------------------------------- k_upd
// Same chunked structure: K=512 in 8 chunks (h bf16 copy; upd fp32 + cvt).
__global__ __launch_bounds__(256, 3) void k_upd(const unsigned short* __restrict__ hbf,
                                                const float* __restrict__ upd,
                                                const unsigned short* __restrict__ W1T,
                                                const float* __restrict__ b1,
                                                const unsigned short* __restrict__ W2T,
                                                const float* __restrict__ b2,
                                                unsigned short* __restrict__ hout) {
    __shared__ __align__(16) unsigned char smem[SMEM_BYTES];
    unsigned short (*As)[64 * 64] =
        reinterpret_cast<unsigned short (*)[64 * 64]>(smem);
    unsigned short* Ts = reinterpret_cast<unsigned short*>(smem);

    const int tid = threadIdx.x;
    const int n0  = blockIdx.x * 64;
    const int lane = tid & 63, wv = tid >> 6;
    const int lr = lane & 15, lq = lane >> 4;
    const int arow = tid & 63;
    const int aoff = (tid >> 6) * 16;
    const int node = (n0 + arow < N_NODES) ? (n0 + arow) : (N_NODES - 1);

    const unsigned short* bp1 = W1T + (size_t)(wv * 64 + lr) * 32 + lq * 8;
    const unsigned short* bp2 = W2T + (size_t)(wv * 64 + lr) * 32 + lq * 8;

    f32x4 acc[4][4];
    #pragma unroll
    for (int i = 0; i < 4; ++i)
        #pragma unroll
        for (int j = 0; j < 4; ++j) acc[i][j] = (f32x4)(0.0f);

    // load helper: chunk c -> two s16x8
    #define ULOAD(c, oa, ob)  do { \
        if ((c) < 4) { \
            const unsigned short* ap = hbf + (size_t)node * HID + (c) * 64 + aoff; \
            (oa) = *(const s16x8*)(ap); (ob) = *(const s16x8*)(ap + 8); \
        } else { \
            const float* up = upd + (size_t)node * HID + ((c) - 4) * 64 + aoff; \
            (oa) = pack8(*(const float4*)(up),     *(const float4*)(up + 4)); \
            (ob) = pack8(*(const float4*)(up + 8), *(const float4*)(up + 12)); \
        } } while (0)

    {
        s16x8 t0, t1;
        ULOAD(0, t0, t1);
        *(s16x8*)&As[0][AIDX(arow, 2 * wv)]     = t0;
        *(s16x8*)&As[0][AIDX(arow, 2 * wv + 1)] = t1;
    }
    s16x8 rNa, rNb, rFa, rFb;
    ULOAD(1, rNa, rNb);
    s16x8 bfr[4], nb[4];
    #pragma unroll
    for (int nf = 0; nf < 4; ++nf)
        bfr[nf] = *(const s16x8*)(bp1 + nf * 512);
    __syncthreads();

    for (int c = 0; c < 8; ++c) {
        if (c + 2 < 8) ULOAD(c + 2, rFa, rFb);
        #pragma unroll
        for (int ksub = 0; ksub < 2; ++ksub) {
            const int t = c * 2 + ksub;
            s16x8 af[4];
            #pragma unroll
            for (int mf = 0; mf < 4; ++mf)
                af[mf] = *(const s16x8*)&As[c & 1][AIDX(mf * 16 + lr, ksub * 4 + lq)];
            if (t + 1 < 16) {
                #pragma unroll
                for (int nf = 0; nf < 4; ++nf)
                    nb[nf] = *(const s16x8*)(bp1 + (size_t)(t + 1) * TILE_SH + nf * 512);
            }
            #pragma unroll
            for (int mf = 0; mf < 4; ++mf)
                #pragma unroll
                for (int nf = 0; nf < 4; ++nf)
                    acc[mf][nf] = __builtin_amdgcn_mfma_f32_16x16x32_bf16(
                        af[mf], bfr[nf], acc[mf][nf], 0, 0, 0);
            if (t + 1 < 16) {
                #pragma unroll
                for (int nf = 0; nf < 4; ++nf) bfr[nf] = nb[nf];
            }
        }
        if (c + 1 < 8) {
            *(s16x8*)&As[(c + 1) & 1][AIDX(arow, 2 * wv)]     = rNa;
            *(s16x8*)&As[(c + 1) & 1][AIDX(arow, 2 * wv + 1)] = rNb;
            rNa = rFa; rNb = rFb;
            __syncthreads();
        }
    }
    #undef ULOAD

    // all waves must finish As reads before Ts (aliased) is written
    __syncthreads();

    #pragma unroll
    for (int nf = 0; nf < 4; ++nf) {
        const int col = wv * 64 + nf * 16 + lr;
        const float bb = b1[col];
        #pragma unroll
        for (int mf = 0; mf < 4; ++mf)
            #pragma unroll
            for (int r = 0; r < 4; ++r) {
                const int row = mf * 16 + lq * 4 + r;
                Ts[row * 264 + col] = f2bu(fmaxf(acc[mf][nf][r] + bb, 0.f));
            }
    }
    __syncthreads();

    f32x4 acc2[4][4];
    #pragma unroll
    for (int i = 0; i < 4; ++i)
        #pragma unroll
        for (int j = 0; j < 4; ++j) acc2[i][j] = (f32x4)(0.0f);

    s16x8 b2f[4], n2b[4];
    #pragma unroll
    for (int nf = 0; nf < 4; ++nf)
        b2f[nf] = *(const s16x8*)(bp2 + nf * 512);

    for (int s = 0; s < 8; ++s) {
        s16x8 a2[4];
        #pragma unroll
        for (int mf = 0; mf < 4; ++mf)
            a2[mf] = *(const s16x8*)&Ts[(mf * 16 + lr) * 264 + s * 32 + lq * 8];
        if (s + 1 < 8) {
            #pragma unroll
            for (int nf = 0; nf < 4; ++nf)
                n2b[nf] = *(const s16x8*)(bp2 + (size_t)(s + 1) * TILE_SH + nf * 512);
        }
        #pragma unroll
        for (int mf = 0; mf < 4; ++mf)
            #pragma unroll
            for (int nf = 0; nf < 4; ++nf)
                acc2[mf][nf] = __builtin_amdgcn_mfma_f32_16x16x32_bf16(
                    a2[mf], b2f[nf], acc2[mf][nf], 0, 0, 0);
        if (s + 1 < 8) {
            #pragma unroll
            for (int nf = 0; nf < 4; ++nf) b2f[nf] = n2b[nf];
        }
    }

    #pragma unroll
    for (int nf = 0; nf < 4; ++nf) {
        const int col = wv * 64 + nf * 16 + lr;
        const float bb = b2[col];
        #pragma unroll
        for (int mf = 0; mf < 4; ++mf)
            #pragma unroll
            for (int r = 0; r < 4; ++r) {
                const int row = mf * 16 + lq * 4 + r;
                const int n = n0 + row;
                if (n < N_NODES)
                    hout[(size_t)n * HID + col] = f2bu(fmaxf(acc2[mf][nf][r] + bb, 0.f));
            }
    }
}

// ---------------------------------------------------------------- k_graph (bf16 h in)
__global__ __launch_bounds__(256) void k_graph(const unsigned short* __restrict__ h,
                                               const int* __restrict__ n2g,
                                               float* __restrict__ out) {
    __shared__ int Sg[64];
    const int tid = threadIdx.x;
    const int n0  = blockIdx.x * 64;
    if (tid < 64) {
        const int n = n0 + tid;
        Sg[tid] = (n < N_NODES) ? n2g[n] : -1;
    }
    __syncthreads();
    const int col = tid;
    float accv = 0.f;
    int curg = Sg[0];
    for (int r = 0; r < 64; ++r) {
        const int n = n0 + r;
        if (n >= N_NODES) break;
        const int g = Sg[r];
        if (g != curg) {
            atomicAdd(&out[(size_t)curg * HID + col], accv);
            accv = 0.f; curg = g;
        }
        accv += bu2f(h[(size_t)n * HID + col]);
    }
    atomicAdd(&out[(size_t)curg * HID + col], accv);
}

// ---------------------------------------------------------------- launch
extern "C" void kernel_launch(void* const* d_in, const int* in_sizes, int n_in,
                              void* d_out, int out_size, void* d_ws, size_t ws_size,
                              hipStream_t stream) {
    const float* x    = (const float*)d_in[0];
    const float* sf   = (const float*)d_in[1];
    const float* ef   = (const float*)d_in[2];
    const float* ew   = (const float*)d_in[3];
    const int*   el   = (const int*)d_in[4];
    const int*   n2g  = (const int*)d_in[5];
    const float* Wlin = (const float*)d_in[6];
    const float* blin = (const float*)d_in[7];
    const float* mW1  = (const float*)d_in[8];
    const float* mb1  = (const float*)d_in[9];
    const float* mW2  = (const float*)d_in[10];
    const float* mb2  = (const float*)d_in[11];
    const float* uW1  = (const float*)d_in[12];
    const float* ub1  = (const float*)d_in[13];
    const float* uW2  = (const float*)d_in[14];
    const float* ub2  = (const float*)d_in[15];
    float* out = (float*)d_out;

    unsigned short* hA   = (unsigned short*)d_ws;                  // N_NODES*HID bf16
    unsigned short* hB   = hA + (size_t)N_NODES * HID;
    unsigned short* efbf = hB + (size_t)N_NODES * HID;             // N_EDGES*EDGE_DIM bf16
    unsigned short* msgW1T = efbf + (size_t)N_EDGES * EDGE_DIM;    // 3*18*8192
    unsigned short* msgW2T = msgW1T + (size_t)3 * 18 * TILE_SH;    // 3*8*8192
    unsigned short* updW1T = msgW2T + (size_t)3 * 8  * TILE_SH;    // 3*16*8192
    unsigned short* updW2T = updW1T + (size_t)3 * 16 * TILE_SH;    // 3*8*8192
    float* upd  = (float*)(updW2T + (size_t)3 * 8 * TILE_SH);      // N_NODES*HID f32
    int* deg    = (int*)(upd + (size_t)N_NODES * HID);
    int* off    = deg + N_NODES;
    int* cursor = off + N_NODES;
    int* eidx   = cursor + N_NODES;                                // N_EDGES

    hipMemsetAsync(d_out, 0, (size_t)NUM_GRAPHS * HID * sizeof(float), stream);
    hipMemsetAsync(deg, 0, (size_t)N_NODES * sizeof(int), stream);

    k_deg <<<(N_EDGES + 255) / 256, 256, 0, stream>>>(el, deg);
    k_scan<<<1, 256, 0, stream>>>(deg, off, cursor);
    k_scat<<<(N_EDGES + 255) / 256, 256, 0, stream>>>(el, cursor, eidx);

    k_prep<<<150, 256, 0, stream>>>(mW1, mW2, uW1, uW2,
                                    msgW1T, msgW2T, updW1T, updW2T);
    k_pef <<<N_EDGES * EDGE_DIM / (256 * 8), 256, 0, stream>>>(ef, efbf);
    k_lin <<<N_NODES / 16, 256, 0, stream>>>(x, Wlin, blin, hA);

    unsigned short* hc = hA;
    unsigned short* hn = hB;
    for (int l = 0; l < N_LAYERS; ++l) {
        hipMemsetAsync(upd, 0, (size_t)N_NODES * HID * sizeof(float), stream);
        k_msg<<<N_EDGES / 64, 256, 0, stream>>>(
            hc, sf, efbf, ew, el, eidx,
            msgW1T + (size_t)l * 18 * TILE_SH,
            mW1 + (size_t)l * 578 * 256, mb1 + (size_t)l * HID,
            msgW2T + (size_t)l * 8 * TILE_SH, mb2 + (size_t)l * HID, upd);
        k_upd<<<(N_NODES + 63) / 64, 256, 0, stream>>>(
            hc, upd,
            updW1T + (size_t)l * 16 * TILE_SH, ub1 + (size_t)l * HID,
            updW2T + (size_t)l * 8 * TILE_SH,  ub2 + (size_t)l * HID, hn);
        unsigned short* t = hc; hc = hn; hn = t;
    }

    k_graph<<<(N_NODES + 63) / 64, 256, 0, stream>>>(hc, n2g, out);
}